// Round 1
// baseline (619.379 us; speedup 1.0000x reference)
//
#include <hip/hip_runtime.h>

#define G 4096
#define B 8192

// ws layout (floats): [0..G-1] = v_mag, [G] = total, [G+1] = edge count (as uint bits)

__global__ void init_ws(float* __restrict__ ws) {
    int i = blockIdx.x * blockDim.x + threadIdx.x;
    if (i < G + 2) ws[i] = 0.0f;
}

// Column-wise mean of |velocity|: each thread owns 4 consecutive columns over a
// 64-row stripe. float4 loads -> fully coalesced 16B/lane.
__global__ __launch_bounds__(256) void vmag_kernel(const float* __restrict__ vel,
                                                   float* __restrict__ vmag) {
    const int col0 = blockIdx.x * 1024 + threadIdx.x * 4;
    const int row0 = blockIdx.y * 64;
    const float* p = vel + (size_t)row0 * G + col0;
    float ax = 0.f, ay = 0.f, az = 0.f, aw = 0.f;
#pragma unroll 4
    for (int r = 0; r < 64; ++r) {
        float4 v = *(const float4*)p;
        ax += fabsf(v.x);
        ay += fabsf(v.y);
        az += fabsf(v.z);
        aw += fabsf(v.w);
        p += G;
    }
    const float s = 1.0f / (float)B;
    atomicAdd(&vmag[col0 + 0], ax * s);
    atomicAdd(&vmag[col0 + 1], ay * s);
    atomicAdd(&vmag[col0 + 2], az * s);
    atomicAdd(&vmag[col0 + 3], aw * s);
}

// Pairwise pass over grn_adj: one float4 per thread. i = row (TF), j = col (target).
// pos edge: |v[j]-v[i]|, neg edge: v[j]+v[i] (v_mag >= 0 so abs is free).
__global__ __launch_bounds__(256) void pair_kernel(const float* __restrict__ adj,
                                                   const float* __restrict__ vmag,
                                                   float* __restrict__ total,
                                                   unsigned int* __restrict__ cnt) {
    const size_t e = ((size_t)blockIdx.x * 256 + threadIdx.x) * 4;
    const int i = (int)(e >> 12);      // row: e / 4096
    const int j = (int)(e & 4095);     // col: e % 4096 (j..j+3 stay in one row)
    const float4 a = *(const float4*)(adj + e);
    const float vi = vmag[i];
    const float4 vj = *(const float4*)(vmag + j);

    float t = 0.f;
    int n = 0;
    if (a.x != 0.f) { t += (a.x > 0.f) ? fabsf(vj.x - vi) : (vj.x + vi); ++n; }
    if (a.y != 0.f) { t += (a.y > 0.f) ? fabsf(vj.y - vi) : (vj.y + vi); ++n; }
    if (a.z != 0.f) { t += (a.z > 0.f) ? fabsf(vj.z - vi) : (vj.z + vi); ++n; }
    if (a.w != 0.f) { t += (a.w > 0.f) ? fabsf(vj.w - vi) : (vj.w + vi); ++n; }

    // wave (64-lane) shuffle reduction
#pragma unroll
    for (int off = 32; off > 0; off >>= 1) {
        t += __shfl_down(t, off);
        n += __shfl_down(n, off);
    }
    __shared__ float st[4];
    __shared__ int sn[4];
    const int wave = threadIdx.x >> 6;
    if ((threadIdx.x & 63) == 0) {
        st[wave] = t;
        sn[wave] = n;
    }
    __syncthreads();
    if (threadIdx.x == 0) {
        const float tt = st[0] + st[1] + st[2] + st[3];
        const int nn = sn[0] + sn[1] + sn[2] + sn[3];
        atomicAdd(total, tt);
        atomicAdd(cnt, (unsigned int)nn);
    }
}

__global__ void finalize(const float* __restrict__ total,
                         const unsigned int* __restrict__ cnt,
                         float* __restrict__ out) {
    const float n = (float)*cnt;
    out[0] = (n > 0.f) ? (*total / fmaxf(n, 1.f)) : 0.f;
}

extern "C" void kernel_launch(void* const* d_in, const int* in_sizes, int n_in,
                              void* d_out, int out_size, void* d_ws, size_t ws_size,
                              hipStream_t stream) {
    const float* vel = (const float*)d_in[0];
    // d_in[1] (perturbation_idx) is unused by the reference.
    const float* adj = (const float*)d_in[2];

    float* ws_f = (float*)d_ws;
    float* vmag = ws_f;
    float* total = ws_f + G;
    unsigned int* cnt = (unsigned int*)(ws_f + G + 1);
    float* out = (float*)d_out;

    init_ws<<<(G + 2 + 255) / 256, 256, 0, stream>>>(ws_f);

    dim3 g1(4, 128);  // 4 column-stripes of 1024, 128 row-stripes of 64
    vmag_kernel<<<g1, 256, 0, stream>>>(vel, vmag);

    pair_kernel<<<(G * G) / (256 * 4), 256, 0, stream>>>(adj, vmag, total, cnt);

    finalize<<<1, 1, 0, stream>>>(total, cnt, out);
}

// Round 2
// 245.791 us; speedup vs baseline: 2.5199x; 2.5199x over previous
//
#include <hip/hip_runtime.h>

#define G 4096
#define B 8192
#define STRIPES 128        // 8192 rows / 64 rows per stripe
#define PAIR_BLOCKS 16384  // G*G / (256 threads * 4 elems)

// ---------------- fast path (partials in ws, no contended atomics) ----------------
// ws floats layout:
//   [0, 524288)        vmag partials: part[stripe*G + col]
//   [524288, 528384)   vmag final (G floats)
//   [528384, 544768)   pair partial totals (PAIR_BLOCKS floats)
//   [544768, 561152)   pair partial counts (PAIR_BLOCKS ints)

__global__ __launch_bounds__(256) void vmag_partial(const float* __restrict__ vel,
                                                    float* __restrict__ part) {
    const int col0 = blockIdx.x * 1024 + threadIdx.x * 4;
    const int stripe = blockIdx.y;
    const float* p = vel + (size_t)stripe * 64 * G + col0;
    float ax = 0.f, ay = 0.f, az = 0.f, aw = 0.f;
#pragma unroll 4
    for (int r = 0; r < 64; ++r) {
        float4 v = *(const float4*)p;
        ax += fabsf(v.x);
        ay += fabsf(v.y);
        az += fabsf(v.z);
        aw += fabsf(v.w);
        p += G;
    }
    float4 o; o.x = ax; o.y = ay; o.z = az; o.w = aw;
    *(float4*)(part + (size_t)stripe * G + col0) = o;  // plain store, no atomics
}

__global__ __launch_bounds__(256) void vmag_reduce(const float* __restrict__ part,
                                                   float* __restrict__ vmag) {
    const int col = blockIdx.x * 256 + threadIdx.x;
    float s = 0.f;
#pragma unroll 8
    for (int st = 0; st < STRIPES; ++st) s += part[(size_t)st * G + col];  // coalesced
    vmag[col] = s * (1.0f / (float)B);
}

__global__ __launch_bounds__(256) void pair_kernel(const float* __restrict__ adj,
                                                   const float* __restrict__ vmag,
                                                   float* __restrict__ pt,
                                                   int* __restrict__ pn) {
    const size_t e = ((size_t)blockIdx.x * 256 + threadIdx.x) * 4;
    const int i = (int)(e >> 12);   // row (TF)
    const int j = (int)(e & 4095);  // col (target); j..j+3 stay in one row
    const float4 a = *(const float4*)(adj + e);
    const float vi = vmag[i];
    const float4 vj = *(const float4*)(vmag + j);

    float t = 0.f;
    int n = 0;
    if (a.x != 0.f) { t += (a.x > 0.f) ? fabsf(vj.x - vi) : (vj.x + vi); ++n; }
    if (a.y != 0.f) { t += (a.y > 0.f) ? fabsf(vj.y - vi) : (vj.y + vi); ++n; }
    if (a.z != 0.f) { t += (a.z > 0.f) ? fabsf(vj.z - vi) : (vj.z + vi); ++n; }
    if (a.w != 0.f) { t += (a.w > 0.f) ? fabsf(vj.w - vi) : (vj.w + vi); ++n; }

#pragma unroll
    for (int off = 32; off > 0; off >>= 1) {
        t += __shfl_down(t, off);
        n += __shfl_down(n, off);
    }
    __shared__ float st[4];
    __shared__ int sn[4];
    const int wave = threadIdx.x >> 6;
    if ((threadIdx.x & 63) == 0) { st[wave] = t; sn[wave] = n; }
    __syncthreads();
    if (threadIdx.x == 0) {
        pt[blockIdx.x] = st[0] + st[1] + st[2] + st[3];  // plain store, no atomics
        pn[blockIdx.x] = sn[0] + sn[1] + sn[2] + sn[3];
    }
}

__global__ __launch_bounds__(1024) void finalize_big(const float* __restrict__ pt,
                                                     const int* __restrict__ pn,
                                                     float* __restrict__ out) {
    float t = 0.f;
    int n = 0;
    for (int idx = threadIdx.x; idx < PAIR_BLOCKS; idx += 1024) {
        t += pt[idx];
        n += pn[idx];
    }
#pragma unroll
    for (int off = 32; off > 0; off >>= 1) {
        t += __shfl_down(t, off);
        n += __shfl_down(n, off);
    }
    __shared__ float st[16];
    __shared__ int sn[16];
    const int wave = threadIdx.x >> 6;
    if ((threadIdx.x & 63) == 0) { st[wave] = t; sn[wave] = n; }
    __syncthreads();
    if (threadIdx.x == 0) {
        float tt = 0.f;
        int nn = 0;
#pragma unroll
        for (int k = 0; k < 16; ++k) { tt += st[k]; nn += sn[k]; }
        const float nf = (float)nn;
        out[0] = (nn > 0) ? (tt / fmaxf(nf, 1.f)) : 0.f;
    }
}

// ---------------- fallback path (round-1, known-correct, small ws) ----------------

__global__ void init_ws(float* __restrict__ ws) {
    int i = blockIdx.x * blockDim.x + threadIdx.x;
    if (i < G + 2) ws[i] = 0.0f;
}

__global__ __launch_bounds__(256) void vmag_atomic(const float* __restrict__ vel,
                                                   float* __restrict__ vmag) {
    const int col0 = blockIdx.x * 1024 + threadIdx.x * 4;
    const int row0 = blockIdx.y * 64;
    const float* p = vel + (size_t)row0 * G + col0;
    float ax = 0.f, ay = 0.f, az = 0.f, aw = 0.f;
#pragma unroll 4
    for (int r = 0; r < 64; ++r) {
        float4 v = *(const float4*)p;
        ax += fabsf(v.x); ay += fabsf(v.y); az += fabsf(v.z); aw += fabsf(v.w);
        p += G;
    }
    const float s = 1.0f / (float)B;
    atomicAdd(&vmag[col0 + 0], ax * s);
    atomicAdd(&vmag[col0 + 1], ay * s);
    atomicAdd(&vmag[col0 + 2], az * s);
    atomicAdd(&vmag[col0 + 3], aw * s);
}

__global__ __launch_bounds__(256) void pair_atomic(const float* __restrict__ adj,
                                                   const float* __restrict__ vmag,
                                                   float* __restrict__ total,
                                                   unsigned int* __restrict__ cnt) {
    const size_t e = ((size_t)blockIdx.x * 256 + threadIdx.x) * 4;
    const int i = (int)(e >> 12);
    const int j = (int)(e & 4095);
    const float4 a = *(const float4*)(adj + e);
    const float vi = vmag[i];
    const float4 vj = *(const float4*)(vmag + j);
    float t = 0.f; int n = 0;
    if (a.x != 0.f) { t += (a.x > 0.f) ? fabsf(vj.x - vi) : (vj.x + vi); ++n; }
    if (a.y != 0.f) { t += (a.y > 0.f) ? fabsf(vj.y - vi) : (vj.y + vi); ++n; }
    if (a.z != 0.f) { t += (a.z > 0.f) ? fabsf(vj.z - vi) : (vj.z + vi); ++n; }
    if (a.w != 0.f) { t += (a.w > 0.f) ? fabsf(vj.w - vi) : (vj.w + vi); ++n; }
#pragma unroll
    for (int off = 32; off > 0; off >>= 1) {
        t += __shfl_down(t, off);
        n += __shfl_down(n, off);
    }
    __shared__ float st[4];
    __shared__ int sn[4];
    const int wave = threadIdx.x >> 6;
    if ((threadIdx.x & 63) == 0) { st[wave] = t; sn[wave] = n; }
    __syncthreads();
    if (threadIdx.x == 0) {
        atomicAdd(total, st[0] + st[1] + st[2] + st[3]);
        atomicAdd(cnt, (unsigned int)(sn[0] + sn[1] + sn[2] + sn[3]));
    }
}

__global__ void finalize_small(const float* __restrict__ total,
                               const unsigned int* __restrict__ cnt,
                               float* __restrict__ out) {
    const float n = (float)*cnt;
    out[0] = (n > 0.f) ? (*total / fmaxf(n, 1.f)) : 0.f;
}

// ---------------------------------------------------------------------------------

extern "C" void kernel_launch(void* const* d_in, const int* in_sizes, int n_in,
                              void* d_out, int out_size, void* d_ws, size_t ws_size,
                              hipStream_t stream) {
    const float* vel = (const float*)d_in[0];
    // d_in[1] (perturbation_idx) unused by the reference.
    const float* adj = (const float*)d_in[2];
    float* out = (float*)d_out;
    float* wsf = (float*)d_ws;

    const size_t need = (size_t)(524288 + 4096 + 2 * PAIR_BLOCKS) * 4;
    if (ws_size >= need) {
        float* part = wsf;
        float* vmag = wsf + 524288;
        float* pt   = wsf + 528384;
        int*   pn   = (int*)(wsf + 544768);

        vmag_partial<<<dim3(4, STRIPES), 256, 0, stream>>>(vel, part);
        vmag_reduce<<<G / 256, 256, 0, stream>>>(part, vmag);
        pair_kernel<<<PAIR_BLOCKS, 256, 0, stream>>>(adj, vmag, pt, pn);
        finalize_big<<<1, 1024, 0, stream>>>(pt, pn, out);
    } else {
        float* vmag = wsf;
        float* total = wsf + G;
        unsigned int* cnt = (unsigned int*)(wsf + G + 1);
        init_ws<<<(G + 2 + 255) / 256, 256, 0, stream>>>(wsf);
        dim3 g1(4, 128);
        vmag_atomic<<<g1, 256, 0, stream>>>(vel, vmag);
        pair_atomic<<<(G * G) / (256 * 4), 256, 0, stream>>>(adj, vmag, total, cnt);
        finalize_small<<<1, 1, 0, stream>>>(total, cnt, out);
    }
}